// Round 2
// baseline (530.381 us; speedup 1.0000x reference)
//
#include <hip/hip_runtime.h>
#include <math.h>

#define NUM_NODES 94
#define NP 96            // nodes padded to 96
#define SEQ_LEN 784
#define OUT_CLASSES 10
#define B_BLK 2          // batch elements per block
#define THREADS (NP * B_BLK)   // 192 threads = 3 waves

#define ALPHA 0.5f
#define TWO_GAMMA 0.2f
#define OM2 0.0503551324598949f          // (2*pi/28)^2
#define INV_SQRT_N 0.103142124625879f    // 1/sqrt(94)

// Quad-lane butterfly reduce via DPP (pure VALU, avoids the LDS pipe).
// 0xB1 = quad_perm(1,0,3,2) = xor1 ; 0x4E = quad_perm(2,3,0,1) = xor2
__device__ __forceinline__ float quad_reduce(float x) {
    int v1 = __builtin_amdgcn_mov_dpp(__float_as_int(x), 0xB1, 0xF, 0xF, true);
    x += __int_as_float(v1);
    int v2 = __builtin_amdgcn_mov_dpp(__float_as_int(x), 0x4E, 0xF, 0xF, true);
    x += __int_as_float(v2);
    return x;
}

__global__ __launch_bounds__(THREADS, 2) void horn_kernel(
    const float* __restrict__ input,   // (1024, 784)
    const float* __restrict__ w_ih,    // (94, 1)
    const float* __restrict__ b_ih,    // (94)
    const float* __restrict__ w_hh,    // (94, 94)
    const float* __restrict__ b_hh,    // (94)
    const float* __restrict__ w_ro,    // (10, 94)
    const float* __restrict__ b_ro,    // (10)
    float* __restrict__ out)           // (1024, 10)
{
    __shared__ __align__(16) float ylds[2][B_BLK][NP];     // double-buffered y
    __shared__ __align__(16) float slds[B_BLK][SEQ_LEN];   // input rows

    const int tid = threadIdx.x;
    const int b   = tid / NP;        // local batch index
    const int rem = tid % NP;        // owned node = 4*r + kq
    const int r   = rem >> 2;        // row-quad index 0..23
    const int kq  = rem & 3;         // K-chunk index  0..3
    const int b0  = blockIdx.x * B_BLK;

    // Prefetch input rows into LDS (float4, coalesced).
    {
        const float4* in4 = (const float4*)input;
        float4* s4 = (float4*)&slds[0][0];
        const int n4 = B_BLK * SEQ_LEN / 4;   // 392
        for (int i = tid; i < n4; i += THREADS) {
            int bb = i / (SEQ_LEN / 4);
            int c  = i % (SEQ_LEN / 4);
            s4[i] = in4[(size_t)(b0 + bb) * (SEQ_LEN / 4) + c];
        }
    }

    ylds[0][b][rem] = 0.0f;
    ylds[1][b][rem] = 0.0f;

    // Load w block: rows 4r..4r+3, cols 24*kq..24*kq+23 (zero-padded).
    float w[4][24];
    const int row0 = r * 4;
    const int col0 = kq * 24;
    #pragma unroll
    for (int i = 0; i < 4; i++) {
        const int row = row0 + i;
        #pragma unroll
        for (int c = 0; c < 24; c++) {
            const int col = col0 + c;
            w[i][c] = (row < NUM_NODES && col < NUM_NODES)
                        ? w_hh[row * NUM_NODES + col] : 0.0f;
        }
    }
    const bool active = (rem < NUM_NODES);
    const float wih = active ? w_ih[rem] : 0.0f;
    const float bih = active ? b_ih[rem] : 0.0f;
    const float bhh = active ? b_hh[rem] : 0.0f;

    float x = 0.0f, y = 0.0f;

    __syncthreads();

    int p = 0;
    for (int t = 0; t < SEQ_LEN; t++) {
        // Partial dots for 4 rows over this thread's 24-col K-chunk.
        const float4* yv = (const float4*)&ylds[p][b][col0];  // 96*kq B, 16B-aligned
        float a0 = 0.0f, a1 = 0.0f, a2 = 0.0f, a3 = 0.0f;
        #pragma unroll
        for (int c4 = 0; c4 < 6; c4++) {
            float4 yy = yv[c4];
            a0 += w[0][c4*4+0] * yy.x; a0 += w[0][c4*4+1] * yy.y;
            a0 += w[0][c4*4+2] * yy.z; a0 += w[0][c4*4+3] * yy.w;
            a1 += w[1][c4*4+0] * yy.x; a1 += w[1][c4*4+1] * yy.y;
            a1 += w[1][c4*4+2] * yy.z; a1 += w[1][c4*4+3] * yy.w;
            a2 += w[2][c4*4+0] * yy.x; a2 += w[2][c4*4+1] * yy.y;
            a2 += w[2][c4*4+2] * yy.z; a2 += w[2][c4*4+3] * yy.w;
            a3 += w[3][c4*4+0] * yy.x; a3 += w[3][c4*4+1] * yy.y;
            a3 += w[3][c4*4+2] * yy.z; a3 += w[3][c4*4+3] * yy.w;
        }
        // Quad butterfly: all 4 lanes get each row's full dot.
        a0 = quad_reduce(a0);
        a1 = quad_reduce(a1);
        a2 = quad_reduce(a2);
        a3 = quad_reduce(a3);
        // Lane kq owns node 4r+kq == rem.
        float ir = (kq == 0) ? a0 : ((kq == 1) ? a1 : ((kq == 2) ? a2 : a3));

        float s_t = slds[b][t];
        float A = (s_t * wih + bih + ir + bhh) * INV_SQRT_N;

        float e  = __expf(2.0f * A);
        float th = 1.0f - __fdividef(2.0f, e + 1.0f);

        float accel = ALPHA * th - TWO_GAMMA * y - OM2 * x;
        x += y;          // H = 1
        y += accel;

        ylds[p ^ 1][b][rem] = y;   // padded nodes stay 0
        __syncthreads();
        p ^= 1;
    }

    // Epilogue: out[b][c] = sum_n x[b][n] * w_ro[c][n] + b_ro[c]
    ylds[0][b][rem] = x;
    __syncthreads();

    if (tid < B_BLK * OUT_CLASSES) {
        int bb = tid / OUT_CLASSES;
        int c  = tid % OUT_CLASSES;
        float s = b_ro[c];
        #pragma unroll 2
        for (int j = 0; j < NUM_NODES; j++) {
            s += ylds[0][bb][j] * w_ro[c * NUM_NODES + j];
        }
        out[(size_t)(b0 + bb) * OUT_CLASSES + c] = s;
    }
}

extern "C" void kernel_launch(void* const* d_in, const int* in_sizes, int n_in,
                              void* d_out, int out_size, void* d_ws, size_t ws_size,
                              hipStream_t stream) {
    const float* input = (const float*)d_in[0];
    const float* w_ih  = (const float*)d_in[1];
    const float* b_ih  = (const float*)d_in[2];
    const float* w_hh  = (const float*)d_in[3];
    const float* b_hh  = (const float*)d_in[4];
    const float* w_ro  = (const float*)d_in[5];
    const float* b_ro  = (const float*)d_in[6];
    float* out = (float*)d_out;

    const int batch = in_sizes[0] / SEQ_LEN;   // 1024
    dim3 grid(batch / B_BLK);                  // 512 blocks
    dim3 block(THREADS);                       // 192 threads

    hipLaunchKernelGGL(horn_kernel, grid, block, 0, stream,
                       input, w_ih, b_ih, w_hh, b_hh, w_ro, b_ro, out);
}

// Round 3
// 529.697 us; speedup vs baseline: 1.0013x; 1.0013x over previous
//
#include <hip/hip_runtime.h>
#include <math.h>

#define NUM_NODES 94
#define NP 96            // nodes padded to 96
#define SEQ_LEN 784
#define OUT_CLASSES 10
#define B_BLK 2          // batch elements per block
#define THREADS (NP * B_BLK)   // 192 threads = 3 waves

#define ALPHA 0.5f
#define TWO_GAMMA 0.2f
#define OM2 0.0503551324598949f          // (2*pi/28)^2
#define INV_SQRT_N 0.103142124625879f    // 1/sqrt(94)

// Quad-lane butterfly reduce via DPP (pure VALU, avoids the LDS pipe).
// 0xB1 = quad_perm(1,0,3,2) = xor1 ; 0x4E = quad_perm(2,3,0,1) = xor2
__device__ __forceinline__ float quad_reduce(float x) {
    int v1 = __builtin_amdgcn_mov_dpp(__float_as_int(x), 0xB1, 0xF, 0xF, true);
    x += __int_as_float(v1);
    int v2 = __builtin_amdgcn_mov_dpp(__float_as_int(x), 0x4E, 0xF, 0xF, true);
    x += __int_as_float(v2);
    return x;
}

// Pin to exactly 2 waves/EU so the allocator gets a 256-VGPR budget and the
// 96-float W block stays register-resident (default 8-waves/EU budget = 64
// VGPRs forced a spill in rounds 1-2: VGPR_Count=64 both times).
__global__
__attribute__((amdgpu_waves_per_eu(2, 2)))
__launch_bounds__(THREADS)
void horn_kernel(
    const float* __restrict__ input,   // (1024, 784)
    const float* __restrict__ w_ih,    // (94, 1)
    const float* __restrict__ b_ih,    // (94)
    const float* __restrict__ w_hh,    // (94, 94)
    const float* __restrict__ b_hh,    // (94)
    const float* __restrict__ w_ro,    // (10, 94)
    const float* __restrict__ b_ro,    // (10)
    float* __restrict__ out)           // (1024, 10)
{
    __shared__ __align__(16) float ylds[2][B_BLK][NP];     // double-buffered y
    __shared__ __align__(16) float slds[B_BLK][SEQ_LEN];   // input rows

    const int tid = threadIdx.x;
    const int b   = tid / NP;        // local batch index
    const int rem = tid % NP;        // owned node = 4*r + kq
    const int r   = rem >> 2;        // row-quad index 0..23
    const int kq  = rem & 3;         // K-chunk index  0..3
    const int b0  = blockIdx.x * B_BLK;

    // Prefetch input rows into LDS (float4, coalesced).
    {
        const float4* in4 = (const float4*)input;
        float4* s4 = (float4*)&slds[0][0];
        const int n4 = B_BLK * SEQ_LEN / 4;   // 392
        for (int i = tid; i < n4; i += THREADS) {
            int bb = i / (SEQ_LEN / 4);
            int c  = i % (SEQ_LEN / 4);
            s4[i] = in4[(size_t)(b0 + bb) * (SEQ_LEN / 4) + c];
        }
    }

    ylds[0][b][rem] = 0.0f;
    ylds[1][b][rem] = 0.0f;

    // Load w block: rows 4r..4r+3, cols 24*kq..24*kq+23 (zero-padded).
    float w[4][24];
    const int row0 = r * 4;
    const int col0 = kq * 24;
    #pragma unroll
    for (int i = 0; i < 4; i++) {
        const int row = row0 + i;
        #pragma unroll
        for (int c = 0; c < 24; c++) {
            const int col = col0 + c;
            w[i][c] = (row < NUM_NODES && col < NUM_NODES)
                        ? w_hh[row * NUM_NODES + col] : 0.0f;
        }
    }
    const bool active = (rem < NUM_NODES);
    const float wih = active ? w_ih[rem] : 0.0f;
    const float bih = active ? b_ih[rem] : 0.0f;
    const float bhh = active ? b_hh[rem] : 0.0f;

    float x = 0.0f, y = 0.0f;

    __syncthreads();

    int p = 0;
    for (int t = 0; t < SEQ_LEN; t++) {
        // Partial dots for 4 rows over this thread's 24-col K-chunk.
        const float4* yv = (const float4*)&ylds[p][b][col0];  // 16B-aligned
        float a0 = 0.0f, a1 = 0.0f, a2 = 0.0f, a3 = 0.0f;
        #pragma unroll
        for (int c4 = 0; c4 < 6; c4++) {
            float4 yy = yv[c4];
            a0 += w[0][c4*4+0] * yy.x; a0 += w[0][c4*4+1] * yy.y;
            a0 += w[0][c4*4+2] * yy.z; a0 += w[0][c4*4+3] * yy.w;
            a1 += w[1][c4*4+0] * yy.x; a1 += w[1][c4*4+1] * yy.y;
            a1 += w[1][c4*4+2] * yy.z; a1 += w[1][c4*4+3] * yy.w;
            a2 += w[2][c4*4+0] * yy.x; a2 += w[2][c4*4+1] * yy.y;
            a2 += w[2][c4*4+2] * yy.z; a2 += w[2][c4*4+3] * yy.w;
            a3 += w[3][c4*4+0] * yy.x; a3 += w[3][c4*4+1] * yy.y;
            a3 += w[3][c4*4+2] * yy.z; a3 += w[3][c4*4+3] * yy.w;
        }
        // Quad butterfly: all 4 lanes get each row's full dot.
        a0 = quad_reduce(a0);
        a1 = quad_reduce(a1);
        a2 = quad_reduce(a2);
        a3 = quad_reduce(a3);
        // Lane kq owns node 4r+kq == rem.
        float ir = (kq == 0) ? a0 : ((kq == 1) ? a1 : ((kq == 2) ? a2 : a3));

        float s_t = slds[b][t];
        float A = (s_t * wih + bih + ir + bhh) * INV_SQRT_N;

        float e  = __expf(2.0f * A);
        float th = 1.0f - __fdividef(2.0f, e + 1.0f);

        float accel = ALPHA * th - TWO_GAMMA * y - OM2 * x;
        x += y;          // H = 1
        y += accel;

        ylds[p ^ 1][b][rem] = y;   // padded nodes stay 0
        __syncthreads();
        p ^= 1;
    }

    // Epilogue: out[b][c] = sum_n x[b][n] * w_ro[c][n] + b_ro[c]
    ylds[0][b][rem] = x;
    __syncthreads();

    if (tid < B_BLK * OUT_CLASSES) {
        int bb = tid / OUT_CLASSES;
        int c  = tid % OUT_CLASSES;
        float s = b_ro[c];
        #pragma unroll 2
        for (int j = 0; j < NUM_NODES; j++) {
            s += ylds[0][bb][j] * w_ro[c * NUM_NODES + j];
        }
        out[(size_t)(b0 + bb) * OUT_CLASSES + c] = s;
    }
}

extern "C" void kernel_launch(void* const* d_in, const int* in_sizes, int n_in,
                              void* d_out, int out_size, void* d_ws, size_t ws_size,
                              hipStream_t stream) {
    const float* input = (const float*)d_in[0];
    const float* w_ih  = (const float*)d_in[1];
    const float* b_ih  = (const float*)d_in[2];
    const float* w_hh  = (const float*)d_in[3];
    const float* b_hh  = (const float*)d_in[4];
    const float* w_ro  = (const float*)d_in[5];
    const float* b_ro  = (const float*)d_in[6];
    float* out = (float*)d_out;

    const int batch = in_sizes[0] / SEQ_LEN;   // 1024
    dim3 grid(batch / B_BLK);                  // 512 blocks
    dim3 block(THREADS);                       // 192 threads

    hipLaunchKernelGGL(horn_kernel, grid, block, 0, stream,
                       input, w_ih, b_ih, w_hh, b_hh, w_ro, b_ro, out);
}

// Round 4
// 450.813 us; speedup vs baseline: 1.1765x; 1.1750x over previous
//
#include <hip/hip_runtime.h>
#include <math.h>

#define NUM_NODES 94
#define NP 96            // nodes padded to 96
#define SEQ_LEN 784
#define OUT_CLASSES 10
#define THREADS 192      // one batch element per block: 48 row-pairs x 4 K-chunks

#define ALPHA 0.5f
#define TWO_GAMMA 0.2f
#define OM2 0.0503551324598949f          // (2*pi/28)^2
#define INV_SQRT_N 0.103142124625879f    // 1/sqrt(94)

// Quad-lane butterfly reduce via DPP (pure VALU).
// 0xB1 = quad_perm(1,0,3,2) = xor1 ; 0x4E = quad_perm(2,3,0,1) = xor2
__device__ __forceinline__ float quad_reduce(float x) {
    int v1 = __builtin_amdgcn_mov_dpp(__float_as_int(x), 0xB1, 0xF, 0xF, true);
    x += __int_as_float(v1);
    int v2 = __builtin_amdgcn_mov_dpp(__float_as_int(x), 0x4E, 0xF, 0xF, true);
    x += __int_as_float(v2);
    return x;
}

// min 2 waves/EU -> 256-VGPR budget; max 4 allows up to 16 waves/CU.
__global__
__attribute__((amdgpu_waves_per_eu(2, 4)))
__launch_bounds__(THREADS)
void horn_kernel(
    const float* __restrict__ input,   // (1024, 784)
    const float* __restrict__ w_ih,    // (94, 1)
    const float* __restrict__ b_ih,    // (94)
    const float* __restrict__ w_hh,    // (94, 94)
    const float* __restrict__ b_hh,    // (94)
    const float* __restrict__ w_ro,    // (10, 94)
    const float* __restrict__ b_ro,    // (10)
    float* __restrict__ out)           // (1024, 10)
{
    __shared__ __align__(16) float ylds[2][NP];      // double-buffered y
    __shared__ __align__(16) float slds[SEQ_LEN];    // this block's input row

    const int tid = threadIdx.x;
    const int q   = tid >> 2;        // row-pair index 0..47 (rows 2q, 2q+1)
    const int kq  = tid & 3;         // K-chunk index 0..3 (cols 24*kq..)
    const int bb  = blockIdx.x;      // batch element

    // Prefetch input row into LDS (float4, coalesced).
    {
        const float4* in4 = (const float4*)(input + (size_t)bb * SEQ_LEN);
        float4* s4 = (float4*)&slds[0];
        for (int i = tid; i < SEQ_LEN / 4; i += THREADS) s4[i] = in4[i];
    }
    if (tid < NP) { ylds[0][tid] = 0.0f; ylds[1][tid] = 0.0f; }

    // Load w block: rows 2q,2q+1, cols 24*kq..24*kq+23 (zero-padded).
    float w[2][24];
    const int row0 = q * 2;
    const int col0 = kq * 24;
    #pragma unroll
    for (int i = 0; i < 2; i++) {
        const int row = row0 + i;
        #pragma unroll
        for (int c = 0; c < 24; c++) {
            const int col = col0 + c;
            w[i][c] = (row < NUM_NODES && col < NUM_NODES)
                        ? w_hh[row * NUM_NODES + col] : 0.0f;
        }
    }
    // Pin W in registers: an asm output cannot be rematerialized from
    // global memory, so the allocator must keep these 48 values resident
    // (rounds 2-3: compiler folded the W loads back into the step loop,
    // re-reading 384 B/thread/step from L1 -> ~1150 cyc/step/CU).
    #pragma unroll
    for (int i = 0; i < 2; i++)
        #pragma unroll
        for (int c = 0; c < 24; c++)
            asm volatile("" : "+v"(w[i][c]));

    // This lane's dynamics row: n_own = 2q + (kq&1); lanes kq and kq+2 duplicate.
    const int n_own = row0 + (kq & 1);
    const bool active = (n_own < NUM_NODES);
    const float wih  = active ? w_ih[n_own] : 0.0f;
    const float bias = active ? (b_ih[n_own] + b_hh[n_own]) : 0.0f;

    float x = 0.0f, y = 0.0f;

    __syncthreads();

    int p = 0;
    for (int t = 0; t < SEQ_LEN; t++) {
        // Partial dots for rows 2q,2q+1 over this lane's 24-col chunk.
        const float4* yv = (const float4*)&ylds[p][col0];   // 16B-aligned
        float a0a = 0.f, a0b = 0.f, a1a = 0.f, a1b = 0.f;   // 2 chains/row
        #pragma unroll
        for (int c4 = 0; c4 < 3; c4++) {
            float4 u = yv[2 * c4];
            float4 v = yv[2 * c4 + 1];
            a0a += w[0][c4*8+0] * u.x; a0a += w[0][c4*8+1] * u.y;
            a0a += w[0][c4*8+2] * u.z; a0a += w[0][c4*8+3] * u.w;
            a0b += w[0][c4*8+4] * v.x; a0b += w[0][c4*8+5] * v.y;
            a0b += w[0][c4*8+6] * v.z; a0b += w[0][c4*8+7] * v.w;
            a1a += w[1][c4*8+0] * u.x; a1a += w[1][c4*8+1] * u.y;
            a1a += w[1][c4*8+2] * u.z; a1a += w[1][c4*8+3] * u.w;
            a1b += w[1][c4*8+4] * v.x; a1b += w[1][c4*8+5] * v.y;
            a1b += w[1][c4*8+6] * v.z; a1b += w[1][c4*8+7] * v.w;
        }
        float a0 = quad_reduce(a0a + a0b);   // full dot of row 2q
        float a1 = quad_reduce(a1a + a1b);   // full dot of row 2q+1
        float ir = (kq & 1) ? a1 : a0;       // this lane's row

        float s_t = slds[t];
        float A = (s_t * wih + bias + ir) * INV_SQRT_N;

        float e  = __expf(2.0f * A);
        float th = 1.0f - __fdividef(2.0f, e + 1.0f);

        float accel = ALPHA * th - TWO_GAMMA * y - OM2 * x;
        x += y;          // H = 1
        y += accel;

        if (kq < 2) ylds[p ^ 1][n_own] = y;  // kq 0/1 cover nodes 2q/2q+1
        __syncthreads();
        p ^= 1;
    }

    // Epilogue: out[bb][c] = sum_n x[n] * w_ro[c][n] + b_ro[c]
    if (kq < 2) ylds[0][n_own] = x;
    __syncthreads();

    if (tid < 4 * OUT_CLASSES) {
        int c   = tid >> 2;
        int kq2 = tid & 3;
        float s = 0.0f;
        #pragma unroll
        for (int i = 0; i < 24; i++) {
            int j = kq2 * 24 + i;
            if (j < NUM_NODES) s += ylds[0][j] * w_ro[c * NUM_NODES + j];
        }
        s = quad_reduce(s);
        if (kq2 == 0) out[(size_t)bb * OUT_CLASSES + c] = s + b_ro[c];
    }
}

extern "C" void kernel_launch(void* const* d_in, const int* in_sizes, int n_in,
                              void* d_out, int out_size, void* d_ws, size_t ws_size,
                              hipStream_t stream) {
    const float* input = (const float*)d_in[0];
    const float* w_ih  = (const float*)d_in[1];
    const float* b_ih  = (const float*)d_in[2];
    const float* w_hh  = (const float*)d_in[3];
    const float* b_hh  = (const float*)d_in[4];
    const float* w_ro  = (const float*)d_in[5];
    const float* b_ro  = (const float*)d_in[6];
    float* out = (float*)d_out;

    const int batch = in_sizes[0] / SEQ_LEN;   // 1024
    dim3 grid(batch);                          // 1024 blocks (1 elem each)
    dim3 block(THREADS);                       // 192 threads

    hipLaunchKernelGGL(horn_kernel, grid, block, 0, stream,
                       input, w_ih, b_ih, w_hh, b_hh, w_ro, b_ro, out);
}

// Round 5
// 427.863 us; speedup vs baseline: 1.2396x; 1.0536x over previous
//
#include <hip/hip_runtime.h>
#include <math.h>

#define NUM_NODES 94
#define NP 96
#define SEQ_LEN 784
#define OUT_CLASSES 10
#define THREADS 192      // q (row-quad 0..23) x kq (K-eighth 0..7)

#define TWO_GAMMA 0.2f
#define OM2 0.0503551324598949f          // (2*pi/28)^2
#define INV_SQRT_N 0.103142124625879f    // 1/sqrt(94)
#define KS (2.0f * INV_SQRT_N)           // folded into w', wih', bias'

typedef float f2 __attribute__((ext_vector_type(2)));

// DPP add: 0xB1 = quad_perm xor1, 0x4E = quad_perm xor2, 0x141 = ROW_HALF_MIRROR (xor4 within 8)
__device__ __forceinline__ float dpp_add(float x, const int ctrl) {
    int t;
    switch (ctrl) {  // ctrl must be a literal constant per call site
        case 0xB1:  t = __builtin_amdgcn_mov_dpp(__float_as_int(x), 0xB1,  0xF, 0xF, true); break;
        case 0x4E:  t = __builtin_amdgcn_mov_dpp(__float_as_int(x), 0x4E,  0xF, 0xF, true); break;
        default:    t = __builtin_amdgcn_mov_dpp(__float_as_int(x), 0x141, 0xF, 0xF, true); break;
    }
    return x + __int_as_float(t);
}

__global__ __launch_bounds__(THREADS, 3)
void horn_kernel(
    const float* __restrict__ input,   // (1024, 784)
    const float* __restrict__ w_ih,    // (94, 1)
    const float* __restrict__ b_ih,    // (94)
    const float* __restrict__ w_hh,    // (94, 94)
    const float* __restrict__ b_hh,    // (94)
    const float* __restrict__ w_ro,    // (10, 94)
    const float* __restrict__ b_ro,    // (10)
    float* __restrict__ out)           // (1024, 10)
{
    __shared__ __align__(16) float ylds[2][NP];     // double-buffered y
    __shared__ __align__(16) float slds[SEQ_LEN];   // this block's input row
    __shared__ __align__(16) float wlds[96][48];    // W round-trip staging (18 KB)

    const int tid = threadIdx.x;
    const int q   = tid >> 3;        // 0..23 -> rows 4q..4q+3
    const int kq  = tid & 7;         // 0..7  -> cols 12*kq..12*kq+11
    const int bb  = blockIdx.x;      // batch element

    // Prefetch input row (float4, coalesced).
    {
        const float4* in4 = (const float4*)(input + (size_t)bb * SEQ_LEN);
        float4* s4 = (float4*)slds;
        for (int i = tid; i < SEQ_LEN / 4; i += THREADS) s4[i] = in4[i];
    }
    if (tid < NP) { ylds[0][tid] = 0.0f; ylds[1][tid] = 0.0f; }

    // Load W block (pre-scaled by KS): rows 4q..4q+3, cols 12kq..12kq+11.
    const int row0 = q * 4, col0 = kq * 12;
    f2 w2[4][6];
    #pragma unroll
    for (int i = 0; i < 4; i++) {
        const int rr = row0 + i;
        #pragma unroll
        for (int c = 0; c < 12; c++) {
            const int cc = col0 + c;
            float v = (rr < NUM_NODES && cc < NUM_NODES)
                        ? w_hh[rr * NUM_NODES + cc] * KS : 0.0f;
            w2[i][c >> 1][c & 1] = v;
        }
    }
    // LDS round-trip in 2 phases (18 KB buffer): an LDS read after a barrier
    // cannot be rematerialized, so W must stay register-resident in the loop.
    // (R2-R4: compiler re-fetched W from L1 or bounced it through AGPRs.)
    {
        const int half = tid / 96;
        const int idx  = tid - half * 96;
        #pragma unroll
        for (int ph = 0; ph < 2; ph++) {
            if (half == ph) {
                #pragma unroll
                for (int i = 0; i < 4; i++)
                    #pragma unroll
                    for (int j = 0; j < 6; j++) {
                        wlds[idx][i * 12 + 2 * j]     = w2[i][j][0];
                        wlds[idx][i * 12 + 2 * j + 1] = w2[i][j][1];
                    }
            }
            __syncthreads();
            if (half == ph) {
                #pragma unroll
                for (int i = 0; i < 4; i++)
                    #pragma unroll
                    for (int j = 0; j < 6; j++) {
                        f2 v; v[0] = wlds[idx][i * 12 + 2 * j];
                              v[1] = wlds[idx][i * 12 + 2 * j + 1];
                        w2[i][j] = v;
                    }
            }
            __syncthreads();
        }
    }

    // Mirror-symmetric row ownership: lanes kq and 7-kq own the same row,
    // so the final ROW_HALF_MIRROR add completes that row's 8-lane sum.
    const int rs   = (kq & 3) ^ ((kq >> 2) * 3);   // 0..3
    const int nown = row0 + rs;
    const bool writer = (kq < 4);
    const bool act    = (nown < NUM_NODES);
    const float wih   = act ? w_ih[nown] * KS : 0.0f;
    const float bias  = act ? (b_ih[nown] + b_hh[nown]) * KS : 0.0f;

    float x = 0.0f, y = 0.0f;

    __syncthreads();

    #define STEP(PB, TIDX)                                                   \
    {                                                                        \
        const f2* yv = (const f2*)&ylds[PB][col0];                           \
        f2 a0 = {0.f, 0.f}, a1 = {0.f, 0.f}, a2 = {0.f, 0.f}, a3 = {0.f, 0.f}; \
        _Pragma("unroll")                                                    \
        for (int j = 0; j < 6; j++) {                                        \
            f2 yy = yv[j];                                                   \
            a0 += w2[0][j] * yy;                                             \
            a1 += w2[1][j] * yy;                                             \
            a2 += w2[2][j] * yy;                                             \
            a3 += w2[3][j] * yy;                                             \
        }                                                                    \
        float r0 = a0[0] + a0[1], r1 = a1[0] + a1[1];                        \
        float r2 = a2[0] + a2[1], r3 = a3[0] + a3[1];                        \
        r0 = dpp_add(r0, 0xB1); r0 = dpp_add(r0, 0x4E);                      \
        r1 = dpp_add(r1, 0xB1); r1 = dpp_add(r1, 0x4E);                      \
        r2 = dpp_add(r2, 0xB1); r2 = dpp_add(r2, 0x4E);                      \
        r3 = dpp_add(r3, 0xB1); r3 = dpp_add(r3, 0x4E);                      \
        float s01 = (rs & 1) ? r1 : r0;                                      \
        float s23 = (rs & 1) ? r3 : r2;                                      \
        float own = (rs & 2) ? s23 : s01;                                    \
        own = dpp_add(own, 0x141);        /* + partner quad: full 8-lane */  \
        float st = slds[TIDX];                                               \
        float e  = __expf(fmaf(st, wih, bias) + own);   /* e^(2A) */         \
        float rcpv = __builtin_amdgcn_rcpf(e + 1.0f);                        \
        float accel = 0.5f - rcpv;        /* = 0.5*tanh(A), inf-safe */      \
        accel = fmaf(-TWO_GAMMA, y, accel);                                  \
        accel = fmaf(-OM2, x, accel);                                        \
        x += y;                           /* H = 1 */                        \
        y += accel;                                                          \
        if (writer) ylds[PB ^ 1][nown] = y;                                  \
        __syncthreads();                                                     \
    }

    for (int t = 0; t < SEQ_LEN; t += 2) {
        STEP(0, t)
        STEP(1, t + 1)
    }
    #undef STEP

    // Epilogue: stash x (ylds[1] is dead after the last step wrote ylds[0]).
    if (writer) ylds[1][nown] = x;
    __syncthreads();

    if (tid < 4 * OUT_CLASSES) {
        const int c  = tid >> 2;
        const int k2 = tid & 3;
        float s = 0.0f;
        #pragma unroll
        for (int i = 0; i < 24; i++) {
            const int j = k2 * 24 + i;
            if (j < NUM_NODES) s += ylds[1][j] * w_ro[c * NUM_NODES + j];
        }
        s = dpp_add(s, 0xB1);
        s = dpp_add(s, 0x4E);
        if (k2 == 0) out[(size_t)bb * OUT_CLASSES + c] = s + b_ro[c];
    }
}

extern "C" void kernel_launch(void* const* d_in, const int* in_sizes, int n_in,
                              void* d_out, int out_size, void* d_ws, size_t ws_size,
                              hipStream_t stream) {
    const float* input = (const float*)d_in[0];
    const float* w_ih  = (const float*)d_in[1];
    const float* b_ih  = (const float*)d_in[2];
    const float* w_hh  = (const float*)d_in[3];
    const float* b_hh  = (const float*)d_in[4];
    const float* w_ro  = (const float*)d_in[5];
    const float* b_ro  = (const float*)d_in[6];
    float* out = (float*)d_out;

    const int batch = in_sizes[0] / SEQ_LEN;   // 1024
    dim3 grid(batch);                          // 1 batch element per block
    dim3 block(THREADS);

    hipLaunchKernelGGL(horn_kernel, grid, block, 0, stream,
                       input, w_ih, b_ih, w_hh, b_hh, w_ro, b_ro, out);
}